// Round 5
// baseline (559.917 us; speedup 1.0000x reference)
//
#include <hip/hip_runtime.h>
#include <hip/hip_bf16.h>
#include <cstdint>
#include <cstddef>

// ---------------- types / constants ----------------
typedef _Float16 half8 __attribute__((ext_vector_type(8)));
typedef _Float16 half4 __attribute__((ext_vector_type(4)));
typedef _Float16 half2v __attribute__((ext_vector_type(2)));
typedef float floatx4 __attribute__((ext_vector_type(4)));

#define KIN   2608          // gate input dim
#define KP    2624          // padded to 41*64
#define GH    1024          // gate hidden
#define NOUT  80            // H*P
#define NTOK  8192          // B*L
#define HID   2048

__device__ __forceinline__ void async_copy16(const void* gsrc, void* ldst) {
  __builtin_amdgcn_global_load_lds(
      (const __attribute__((address_space(1))) void*)gsrc,
      (__attribute__((address_space(3))) void*)ldst, 16, 0, 0);
}

// ---------------- kernel 0: convert W1/W2 to fp16 (W1 K-padded) ------------
__global__ __launch_bounds__(256) void convertw(
    const float* __restrict__ W1, const float* __restrict__ W2,
    _Float16* __restrict__ W1p, _Float16* __restrict__ W2p)
{
  int i = blockIdx.x * 256 + threadIdx.x;
  const int total1 = GH * KP;         // 2,686,976
  if (i < total1) {
    int n = i / KP;
    int k = i - n * KP;
    W1p[i] = (k < KIN) ? (_Float16)W1[(size_t)n * KIN + k] : (_Float16)0.f;
  } else {
    int j = i - total1;
    if (j < NOUT * GH) W2p[j] = (_Float16)W2[j];
  }
}

// ---------------- kernel 1: stats + hidden->fp16, MLP-first design --------
// one block per token; 16 lanes per head; ALL 12 global loads issued before
// any consumption (10 path float4s + 2 hidden float4s in flight per thread).
__global__ __launch_bounds__(256) void k1_v5(
    const float* __restrict__ hidden,
    const float* __restrict__ p0, const float* __restrict__ p1,
    const float* __restrict__ p2, const float* __restrict__ p3,
    const float* __restrict__ p4,
    _Float16* __restrict__ gate)
{
  const int tid = threadIdx.x;
  const int token = blockIdx.x;
  const int head = tid >> 4;     // 0..15
  const int j = tid & 15;        // lane within head group
  const size_t base = (size_t)token * 2048 + head * 128;
  const float* hrow = hidden + (size_t)token * HID;

  // ---- load phase: 12 independent float4 loads, no consumption between ----
  float4 d[5][2];
  float4 hv0, hv1;
  {
    const float* q0 = p0 + base + j * 4;
    const float* q1 = p1 + base + j * 4;
    const float* q2 = p2 + base + j * 4;
    const float* q3 = p3 + base + j * 4;
    const float* q4 = p4 + base + j * 4;
    d[0][0] = *(const float4*)(q0);      d[0][1] = *(const float4*)(q0 + 64);
    d[1][0] = *(const float4*)(q1);      d[1][1] = *(const float4*)(q1 + 64);
    d[2][0] = *(const float4*)(q2);      d[2][1] = *(const float4*)(q2 + 64);
    d[3][0] = *(const float4*)(q3);      d[3][1] = *(const float4*)(q3 + 64);
    d[4][0] = *(const float4*)(q4);      d[4][1] = *(const float4*)(q4 + 64);
    hv0 = *(const float4*)(hrow + tid * 8);
    hv1 = *(const float4*)(hrow + tid * 8 + 4);
  }

  // ---- consume: per-thread partial stats over 8 elems ----
  float v[5][8];
#pragma unroll
  for (int p = 0; p < 5; ++p) {
    v[p][0] = d[p][0].x; v[p][1] = d[p][0].y; v[p][2] = d[p][0].z; v[p][3] = d[p][0].w;
    v[p][4] = d[p][1].x; v[p][5] = d[p][1].y; v[p][6] = d[p][1].z; v[p][7] = d[p][1].w;
  }
  float s[5], s2[5], sa[5], dt[10];
#pragma unroll
  for (int p = 0; p < 5; ++p) {
    float a = 0.f, b = 0.f, c = 0.f;
#pragma unroll
    for (int e = 0; e < 8; ++e) { float x = v[p][e]; a += x; b += x * x; c += fabsf(x); }
    s[p] = a; s2[p] = b; sa[p] = c;
  }
  {
    int pi = 0;
#pragma unroll
    for (int a = 0; a < 5; ++a)
#pragma unroll
      for (int b = a + 1; b < 5; ++b) {
        float acc = 0.f;
#pragma unroll
        for (int e = 0; e < 8; ++e) acc += v[a][e] * v[b][e];
        dt[pi++] = acc;
      }
  }

  // ---- hidden fp32 -> fp16 store (issued early; independent of shuffles) --
  _Float16* gs = gate + (size_t)token * KP;
  {
    half8 hv;
    hv[0] = (_Float16)hv0.x; hv[1] = (_Float16)hv0.y; hv[2] = (_Float16)hv0.z; hv[3] = (_Float16)hv0.w;
    hv[4] = (_Float16)hv1.x; hv[5] = (_Float16)hv1.y; hv[6] = (_Float16)hv1.z; hv[7] = (_Float16)hv1.w;
    *(half8*)(gs + tid * 8) = hv;
  }

  // ---- butterfly reduce across the 16-lane group ----
#pragma unroll
  for (int p = 0; p < 5; ++p) {
    s[p]  += __shfl_xor(s[p], 1, 16);  s[p]  += __shfl_xor(s[p], 2, 16);
    s[p]  += __shfl_xor(s[p], 4, 16);  s[p]  += __shfl_xor(s[p], 8, 16);
    s2[p] += __shfl_xor(s2[p], 1, 16); s2[p] += __shfl_xor(s2[p], 2, 16);
    s2[p] += __shfl_xor(s2[p], 4, 16); s2[p] += __shfl_xor(s2[p], 8, 16);
    sa[p] += __shfl_xor(sa[p], 1, 16); sa[p] += __shfl_xor(sa[p], 2, 16);
    sa[p] += __shfl_xor(sa[p], 4, 16); sa[p] += __shfl_xor(sa[p], 8, 16);
  }
#pragma unroll
  for (int i = 0; i < 10; ++i) {
    dt[i] += __shfl_xor(dt[i], 1, 16); dt[i] += __shfl_xor(dt[i], 2, 16);
    dt[i] += __shfl_xor(dt[i], 4, 16); dt[i] += __shfl_xor(dt[i], 8, 16);
  }

  // ---- distribute stat writes across lanes of the group ----
  if (j < 5) {
    int p = j;
    float mean = s[p] * (1.f / 128.f);
    float var  = s2[p] * (1.f / 128.f) - mean * mean;
    float am   = sa[p] * (1.f / 128.f);
    float l2   = sqrtf(s2[p]);
    half4 st;
    st[0] = (_Float16)mean; st[1] = (_Float16)var;
    st[2] = (_Float16)am;   st[3] = (_Float16)l2;
    *(half4*)(gs + 2048 + head * 20 + p * 4) = st;
  } else if (j == 5) {
#pragma unroll
    for (int p = 0; p < 5; ++p) gs[2368 + head * 5 + p] = (_Float16)sqrtf(s2[p]);
  } else if (j == 6 || j == 7) {
    int lo = (j == 6) ? 0 : 5;
    int pi = 0;
#pragma unroll
    for (int a = 0; a < 5; ++a)
#pragma unroll
      for (int b = a + 1; b < 5; ++b) {
        if (pi >= lo && pi < lo + 5) {
          float d2 = s2[a] + s2[b] - 2.f * dt[pi];
          gs[2448 + head * 10 + pi] = (_Float16)sqrtf(fmaxf(d2, 0.f));
        }
        ++pi;
      }
  } else if (tid == 8) {
    half8 z = {(_Float16)0.f, (_Float16)0.f, (_Float16)0.f, (_Float16)0.f,
               (_Float16)0.f, (_Float16)0.f, (_Float16)0.f, (_Float16)0.f};
    *(half8*)(gs + 2608) = z;
    *(half8*)(gs + 2616) = z;
  }
}

// ---------------- kernel 2: GEMM1 + bias + exact gelu ----------------------
// C[M=8192, N=1024] = A[M,KP] * W1p[N,KP]^T ; 128x128 tile, BK=64, f16 MFMA
__global__ __launch_bounds__(256) void gemm1(
    const _Float16* __restrict__ A,    // gate [NTOK][KP]
    const _Float16* __restrict__ Bt,   // W1p  [GH][KP]
    const float* __restrict__ b1,
    _Float16* __restrict__ Hm)         // [NTOK][GH]
{
  __shared__ _Float16 As[128 * 64];
  __shared__ _Float16 Bs[128 * 64];
  const int tid  = threadIdx.x;
  const int lane = tid & 63;
  const int wave = tid >> 6;
  const int m0 = blockIdx.x * 128;
  const int n0 = blockIdx.y * 128;
  const int wm = (wave & 1) * 64;
  const int wn = (wave >> 1) * 64;

  floatx4 acc[4][4];
#pragma unroll
  for (int i = 0; i < 4; ++i)
#pragma unroll
    for (int k = 0; k < 4; ++k) acc[i][k] = (floatx4){0.f, 0.f, 0.f, 0.f};

  for (int kt = 0; kt < KP / 64; ++kt) {
    __syncthreads();
    const int kbase = kt * 64;
#pragma unroll
    for (int r = 0; r < 4; ++r) {
      int chunk = r * 256 + tid;        // 0..1023, 16B chunks
      int row = chunk >> 3;             // 0..127
      int kk  = (chunk & 7) * 8;        // fp16 offset in BK
      const _Float16* ga = A  + (size_t)(m0 + row) * KP + kbase + kk;
      const _Float16* gb = Bt + (size_t)(n0 + row) * KP + kbase + kk;
      // wave-uniform LDS base; HW scatters lane i at base + i*16B
      async_copy16(ga, &As[0] + (r * 2048 + wave * 512));
      async_copy16(gb, &Bs[0] + (r * 2048 + wave * 512));
    }
    __syncthreads();
#pragma unroll
    for (int ks = 0; ks < 2; ++ks) {
      half8 af[4], bf[4];
#pragma unroll
      for (int i = 0; i < 4; ++i) {
        int ar = wm + i * 16 + (lane & 15);
        af[i] = *(const half8*)&As[ar * 64 + ks * 32 + (lane >> 4) * 8];
        int br = wn + i * 16 + (lane & 15);
        bf[i] = *(const half8*)&Bs[br * 64 + ks * 32 + (lane >> 4) * 8];
      }
#pragma unroll
      for (int mi = 0; mi < 4; ++mi)
#pragma unroll
        for (int ni = 0; ni < 4; ++ni)
          acc[mi][ni] = __builtin_amdgcn_mfma_f32_16x16x32_f16(af[mi], bf[ni], acc[mi][ni], 0, 0, 0);
    }
  }
  // epilogue: bias + exact gelu -> fp16
#pragma unroll
  for (int mi = 0; mi < 4; ++mi) {
#pragma unroll
    for (int ni = 0; ni < 4; ++ni) {
      int col = n0 + wn + ni * 16 + (lane & 15);
      float bias = b1[col];
#pragma unroll
      for (int r = 0; r < 4; ++r) {
        int row = m0 + wm + mi * 16 + (lane >> 4) * 4 + r;
        float x = acc[mi][ni][r] + bias;
        float g = 0.5f * x * (1.f + erff(x * 0.70710678118654752f));
        Hm[(size_t)row * GH + col] = (_Float16)g;
      }
    }
  }
}

// ---------------- kernel 3: GEMM2 (logits = H * W2^T + b2) -----------------
__global__ __launch_bounds__(256) void gemm2(
    const _Float16* __restrict__ Hm, const _Float16* __restrict__ W2p,
    const float* __restrict__ b2, float* __restrict__ logits)
{
  const int lane = threadIdx.x & 63;
  const int wave = threadIdx.x >> 6;
  const int m0 = blockIdx.x * 64 + wave * 16;
  const int mrow = m0 + (lane & 15);
  const int koff = (lane >> 4) * 8;
  floatx4 acc[5];
#pragma unroll
  for (int i = 0; i < 5; ++i) acc[i] = (floatx4){0.f, 0.f, 0.f, 0.f};
  for (int k0 = 0; k0 < GH; k0 += 32) {
    half8 af = *(const half8*)&Hm[(size_t)mrow * GH + k0 + koff];
#pragma unroll
    for (int ni = 0; ni < 5; ++ni) {
      half8 bf = *(const half8*)&W2p[(size_t)(ni * 16 + (lane & 15)) * GH + k0 + koff];
      acc[ni] = __builtin_amdgcn_mfma_f32_16x16x32_f16(af, bf, acc[ni], 0, 0, 0);
    }
  }
#pragma unroll
  for (int ni = 0; ni < 5; ++ni) {
    int col = ni * 16 + (lane & 15);
    float bias = b2[col];
#pragma unroll
    for (int r = 0; r < 4; ++r) {
      int row = m0 + (lane >> 4) * 4 + r;
      logits[(size_t)row * NOUT + col] = acc[ni][r] + bias;
    }
  }
}

// ---------------- kernel 4: softmax / clip / renorm ------------------------
__global__ __launch_bounds__(256) void softmaxk(
    const float* __restrict__ logits, const float* __restrict__ log_temp,
    float* __restrict__ probs)
{
  int id = blockIdx.x * 256 + threadIdx.x;   // 8192*16 tasks
  int t = id >> 4;
  int h = id & 15;
  float it = __expf(-log_temp[h]);
  const float* lp = logits + (size_t)t * NOUT + h * 5;
  float x[5];
  float m = -1e30f;
#pragma unroll
  for (int p = 0; p < 5; ++p) { x[p] = lp[p] * it; m = fmaxf(m, x[p]); }
  float ssum = 0.f;
#pragma unroll
  for (int p = 0; p < 5; ++p) { x[p] = __expf(x[p] - m); ssum += x[p]; }
  float inv = 1.f / ssum;
  float c = 0.f;
#pragma unroll
  for (int p = 0; p < 5; ++p) { x[p] = fmaxf(x[p] * inv, 0.02f); c += x[p]; }
  float inv2 = 1.f / c;
  float* pp = probs + (size_t)t * NOUT + h * 5;
#pragma unroll
  for (int p = 0; p < 5; ++p) pp[p] = x[p] * inv2;
}

// ---------------- kernel 5: weighted combine, MLP-first --------------------
// 8 lanes per (token,head); each thread: 20 independent path float4 loads
// (4 per path, lane-interleaved for coalescing) + 5 prob scalars in flight.
__global__ __launch_bounds__(256) void k5_v2(
    const float* __restrict__ p0, const float* __restrict__ p1,
    const float* __restrict__ p2, const float* __restrict__ p3,
    const float* __restrict__ p4,
    const float* __restrict__ probs, float* __restrict__ out)
{
  const int tid = threadIdx.x;
  const int unit = blockIdx.x * 32 + (tid >> 3);  // token*16 + head
  const int sub = tid & 7;
  const int token = unit >> 4;
  const int head = unit & 15;
  const size_t base = (size_t)unit * 128;

  // ---- load phase ----
  const float* pb = probs + (size_t)token * NOUT + head * 5;
  float w0 = pb[0], w1 = pb[1], w2 = pb[2], w3 = pb[3], w4 = pb[4];
  float4 a[5][4];
#pragma unroll
  for (int r = 0; r < 4; ++r) {
    size_t off = base + (size_t)(sub + r * 8) * 4;
    a[0][r] = *(const float4*)(p0 + off);
    a[1][r] = *(const float4*)(p1 + off);
    a[2][r] = *(const float4*)(p2 + off);
    a[3][r] = *(const float4*)(p3 + off);
    a[4][r] = *(const float4*)(p4 + off);
  }

  // ---- combine + store ----
#pragma unroll
  for (int r = 0; r < 4; ++r) {
    float4 o;
    o.x = a[0][r].x * w0 + a[1][r].x * w1 + a[2][r].x * w2 + a[3][r].x * w3 + a[4][r].x * w4;
    o.y = a[0][r].y * w0 + a[1][r].y * w1 + a[2][r].y * w2 + a[3][r].y * w3 + a[4][r].y * w4;
    o.z = a[0][r].z * w0 + a[1][r].z * w1 + a[2][r].z * w2 + a[3][r].z * w3 + a[4][r].z * w4;
    o.w = a[0][r].w * w0 + a[1][r].w * w1 + a[2][r].w * w2 + a[3][r].w * w3 + a[4][r].w * w4;
    *(float4*)(out + base + (size_t)(sub + r * 8) * 4) = o;
  }
  if (blockIdx.x == 0 && tid == 0) out[(size_t)NTOK * 2048] = 0.f;   // reg_loss
}

// ---------------- launch ----------------------------------------------------
extern "C" void kernel_launch(void* const* d_in, const int* in_sizes, int n_in,
                              void* d_out, int out_size, void* d_ws, size_t ws_size,
                              hipStream_t stream) {
  const float* hidden  = (const float*)d_in[0];
  const float* p0      = (const float*)d_in[1];
  const float* p1      = (const float*)d_in[2];
  const float* p2      = (const float*)d_in[3];
  const float* p3      = (const float*)d_in[4];
  const float* p4      = (const float*)d_in[5];
  const float* W1      = (const float*)d_in[6];
  const float* b1      = (const float*)d_in[7];
  const float* W2      = (const float*)d_in[8];
  const float* b2      = (const float*)d_in[9];
  const float* logtemp = (const float*)d_in[10];
  float* out = (float*)d_out;

  char* ws = (char*)d_ws;
  _Float16* gate = (_Float16*)(ws);                         // 8192*2624*2 = 42,991,616
  _Float16* W1p  = (_Float16*)(ws + 42991616);              // 1024*2624*2 =  5,373,952
  _Float16* W2p  = (_Float16*)(ws + 48365568);              // 80*1024*2   =    163,840
  _Float16* Hm   = (_Float16*)(ws + 48529408);              // 8192*1024*2 = 16,777,216
  float*    logits = (float*)(ws + 65306624);               // 8192*80*4   =  2,621,440
  float*    probs  = (float*)(ws + 67928064);               // 8192*80*4   =  2,621,440

  convertw<<<10816, 256, 0, stream>>>(W1, W2, W1p, W2p);
  k1_v5<<<NTOK, 256, 0, stream>>>(hidden, p0, p1, p2, p3, p4, gate);
  gemm1<<<dim3(NTOK / 128, GH / 128), 256, 0, stream>>>(gate, W1p, b1, Hm);
  gemm2<<<NTOK / 64, 256, 0, stream>>>(Hm, W2p, b2, logits);
  softmaxk<<<(NTOK * 16) / 256, 256, 0, stream>>>(logits, logtemp, probs);
  k5_v2<<<4096, 256, 0, stream>>>(p0, p1, p2, p3, p4, probs, out);
}